// Round 13
// baseline (310.900 us; speedup 1.0000x reference)
//
#include <hip/hip_runtime.h>
#include <math.h>

// Density-Aware Chamfer Loss, B=4, N=8192, fp32 3D points.
//
// Round-13: partial (MFMA, 45us, absmax 0.0) UNCHANGED from r11/r12.
// dacl_final rewritten: r12's 66us was a scratch spill — float f[48] with
// VGPR_Count=40 meant A2's gather buffer lived in HBM-backed private memory.
// Now: (1) A2 processes 8 targets per step via 6 NAMED float4 (no indexable
// array -> pure VGPRs); (2) 1024 blocks x 4 threads/query (sub = wave id, so
// A1 slot rows stay coalesced per wave; 16 rows/wave); (3) LDS atomicMin
// combines: A1 key = monotone(bits)&~0x3F | group (min -> lowest group on
// ties), A2 key = bits(d)&~0x7F | idx7 (d exact >= 0 -> monotone, first-min).
// Barrier spans 1024 blocks = 4/CU vs capacity >=6/CU -> co-residency slack.
//
// ws: [slot 64grp x 2BN f32 (16.8MB)][cnt 2BN int][arrive int]
// Dispatches: partial(+zero cnt,arrive) -> final(+zero out).   (2 total)

#define NPTS   8192
#define BLK    256
#define QPB    128                  // queries per block (partial; 4 waves x 32)
#define TPS    2048                 // targets per slice
#define TILES  (TPS / 32)           // 64 MFMA tiles per slice
#define NSLICE (NPTS / TPS)         // 4
#define QCH    (NPTS / QPB)         // 64
#define GRP    128                  // targets per slot group
#define NGRP   (NPTS / GRP)         // 64
#define FQ     64                   // queries per final block

typedef __attribute__((ext_vector_type(8)))  short short8;
typedef __attribute__((ext_vector_type(16))) float float16v;

__device__ inline void bsplit(float x, unsigned short& h, unsigned short& l) {
    const unsigned int u = __float_as_uint(x);
    const unsigned short hh = (unsigned short)(u >> 16);   // truncated bf16 hi
    const float lf = x - __uint_as_float((unsigned int)hh << 16);
    h = hh;
    l = (unsigned short)(__float_as_uint(lf) >> 16);       // bf16 lo
}

__global__ __launch_bounds__(BLK) void dacl_partial(
    const float* __restrict__ gts, const float* __restrict__ preds,
    float* __restrict__ slot, int* __restrict__ cnt, int* __restrict__ arrive,
    int B, int N)
{
    const int bz  = blockIdx.z;      // dir*B + b
    const int dir = bz / B;
    const int b   = bz - dir * B;
    const int total = 2 * B * N;

    // fold cnt/arrive zeroing in (first read by dacl_final -> boundary orders)
    if (blockIdx.y == 0) {
        const int per = total / (QCH * 2 * B);             // 128
        int* p = cnt + (blockIdx.x + QCH * bz) * per;
        for (int k = threadIdx.x; k < per; k += BLK) p[k] = 0;
        if (blockIdx.x == 0 && bz == 0 && threadIdx.x == 0) *arrive = 0;
    }

    const float* __restrict__ q = (dir == 0 ? gts : preds) + (size_t)b * N * 3;
    const float* __restrict__ t = (dir == 0 ? preds : gts) + (size_t)b * N * 3;

    __shared__ short8 frag[TILES * 64];                    // 64KB A-frags

    // stage+pack A-frags: 2048 targets, 8 per thread.  MFMA K=13 layout:
    // k0-2 thi.(-2qhi)  k3-5 thi.(-2qlo)  k6-8 tlo.(-2qhi)
    // k9 |t|^2hi.1  k10 |t|^2lo.1  k11 1.|q|^2hi  k12 1.|q|^2lo
    const int sbase = blockIdx.y * TPS;
    for (int rep = 0; rep < TPS / BLK; ++rep) {
        const int tgt = rep * BLK + threadIdx.x;
        const int j   = sbase + tgt;
        const float tx = t[3 * j], ty = t[3 * j + 1], tz = t[3 * j + 2];
        const float t2 = fmaf(tx, tx, fmaf(ty, ty, tz * tz));
        unsigned short hx, lx, hy, ly, hz, lz, h2, l2;
        bsplit(tx, hx, lx); bsplit(ty, hy, ly); bsplit(tz, hz, lz); bsplit(t2, h2, l2);
        union { short8 v; unsigned short s[8]; } k0, k1;
        k0.s[0]=hx; k0.s[1]=hy; k0.s[2]=hz; k0.s[3]=hx; k0.s[4]=hy; k0.s[5]=hz; k0.s[6]=lx; k0.s[7]=ly;
        k1.s[0]=lz; k1.s[1]=h2; k1.s[2]=l2; k1.s[3]=0x3F80; k1.s[4]=0x3F80; k1.s[5]=0; k1.s[6]=0; k1.s[7]=0;
        const int tile = tgt >> 5, row = tgt & 31;
        frag[tile * 64 + row]      = k0.v;                 // k-half 0 (lanes 0-31)
        frag[tile * 64 + 32 + row] = k1.v;                 // k-half 1 (lanes 32-63)
    }

    // B-frag: each wave owns 32 queries; lane&31 = query col (HW-verified
    // col=lane&31, m74/m101), lane>>5 = k-half
    const int lane = threadIdx.x & 63;
    const int wave = threadIdx.x >> 6;
    const int qi   = blockIdx.x * QPB + wave * 32 + (lane & 31);
    const float qx = q[3 * qi], qy = q[3 * qi + 1], qz = q[3 * qi + 2];
    const float q2 = fmaf(qx, qx, fmaf(qy, qy, qz * qz));
    unsigned short shx, slx, shy, sly, shz, slz, h2q, l2q;
    bsplit(-2.0f * qx, shx, slx); bsplit(-2.0f * qy, shy, sly);
    bsplit(-2.0f * qz, shz, slz); bsplit(q2, h2q, l2q);
    union { short8 v; unsigned short s[8]; } bu;
    if ((lane >> 5) == 0) {
        bu.s[0]=shx; bu.s[1]=shy; bu.s[2]=shz; bu.s[3]=slx; bu.s[4]=sly; bu.s[5]=slz; bu.s[6]=shx; bu.s[7]=shy;
    } else {
        bu.s[0]=shz; bu.s[1]=0x3F80; bu.s[2]=0x3F80; bu.s[3]=h2q; bu.s[4]=l2q; bu.s[5]=0; bu.s[6]=0; bu.s[7]=0;
    }
    const short8 bfrag = bu.v;

    __syncthreads();

    const float16v zz = {0.f,0.f,0.f,0.f, 0.f,0.f,0.f,0.f,
                         0.f,0.f,0.f,0.f, 0.f,0.f,0.f,0.f};
    const size_t gq = (size_t)bz * N + qi;
    float gmin = 3.402823466e38f;

    // hot loop: 1 ds_read_b128 + 1 mfma + 9-op min3 tree per 1024 pairs.
    // group-min is invariant to the C/D row permutation.
    #pragma unroll 2
    for (int tile = 0; tile < TILES; ++tile) {
        const short8 av = frag[tile * 64 + lane];
        float16v acc = __builtin_amdgcn_mfma_f32_32x32x16_bf16(av, bfrag, zz, 0, 0, 0);
        const float t0 = fminf(fminf(acc[0],  acc[1]),  acc[2]);
        const float t1 = fminf(fminf(acc[3],  acc[4]),  acc[5]);
        const float t2 = fminf(fminf(acc[6],  acc[7]),  acc[8]);
        const float t3 = fminf(fminf(acc[9],  acc[10]), acc[11]);
        const float t4 = fminf(fminf(acc[12], acc[13]), acc[14]);
        const float u0 = fminf(fminf(t0, t1), acc[15]);
        const float u1 = fminf(fminf(t2, t3), t4);
        gmin = fminf(gmin, fminf(u0, u1));
        if ((tile & 3) == 3) {                             // close a 128-target group
            const float o = fminf(gmin, __shfl_xor(gmin, 32, 64));  // both row-halves
            if (lane < 32)
                slot[(size_t)(blockIdx.y * (TILES / 4) + (tile >> 2)) * total + gq] = o;
            gmin = 3.402823466e38f;
        }
    }
}

// 8 exact distances from 6 named float4 (24 floats, 12B per target) — no array
#define DIST8(V0,V1,V2,V3,V4,V5,BASE)                                          \
    do {                                                                       \
        const float d0 = sq3(qx-(V0).x, qy-(V0).y, qz-(V0).z);                 \
        const float d1 = sq3(qx-(V0).w, qy-(V1).x, qz-(V1).y);                 \
        const float d2 = sq3(qx-(V1).z, qy-(V1).w, qz-(V2).x);                 \
        const float d3 = sq3(qx-(V2).y, qy-(V2).z, qz-(V2).w);                 \
        const float d4 = sq3(qx-(V3).x, qy-(V3).y, qz-(V3).z);                 \
        const float d5 = sq3(qx-(V3).w, qy-(V4).x, qz-(V4).y);                 \
        const float d6 = sq3(qx-(V4).z, qy-(V4).w, qz-(V5).x);                 \
        const float d7 = sq3(qx-(V5).y, qy-(V5).z, qz-(V5).w);                 \
        best = min(best, (__float_as_uint(d0) & 0xFFFFFF80u) | (unsigned)((BASE)+0)); \
        best = min(best, (__float_as_uint(d1) & 0xFFFFFF80u) | (unsigned)((BASE)+1)); \
        best = min(best, (__float_as_uint(d2) & 0xFFFFFF80u) | (unsigned)((BASE)+2)); \
        best = min(best, (__float_as_uint(d3) & 0xFFFFFF80u) | (unsigned)((BASE)+3)); \
        best = min(best, (__float_as_uint(d4) & 0xFFFFFF80u) | (unsigned)((BASE)+4)); \
        best = min(best, (__float_as_uint(d5) & 0xFFFFFF80u) | (unsigned)((BASE)+5)); \
        best = min(best, (__float_as_uint(d6) & 0xFFFFFF80u) | (unsigned)((BASE)+6)); \
        best = min(best, (__float_as_uint(d7) & 0xFFFFFF80u) | (unsigned)((BASE)+7)); \
    } while (0)

__device__ inline float sq3(float x, float y, float z) {
    return fmaf(x, x, fmaf(y, y, z * z));
}

// merge + count + loss fused; 1024 blocks (4/CU, capacity >=6/CU -> safe spin)
__global__ __launch_bounds__(BLK) void dacl_final(
    const float* __restrict__ gts, const float* __restrict__ preds,
    const float* __restrict__ slot, int* __restrict__ cnt,
    int* __restrict__ arrive, float* __restrict__ out, int out_size,
    int B, int N)
{
    const int tid  = threadIdx.x;
    const int lane = tid & 63;       // local query 0..63
    const int wv   = tid >> 6;       // sub-worker 0..3
    const int total = 2 * B * N;
    const int g0   = blockIdx.x * FQ;                      // first query of block
    const int bz   = g0 / N;                               // block-uniform
    const int dir  = bz / B;
    const int b    = bz - dir * B;
    const float* __restrict__ q = (dir == 0 ? gts : preds) + (size_t)b * N * 3;
    const float* __restrict__ t = (dir == 0 ? preds : gts) + (size_t)b * N * 3;

    __shared__ unsigned int smin[FQ];   // A1 combine: trunc-monotone | group
    __shared__ unsigned int skey[FQ];   // A2 combine: bits(d)&~0x7F | idx7

    if (blockIdx.x == 0 && tid < out_size) out[tid] = 0.0f;
    if (tid < FQ) { smin[tid] = 0xFFFFFFFFu; skey[tid] = 0xFFFFFFFFu; }
    __syncthreads();

    const int g = g0 + lane;                               // this query id

    // A1: wave wv scans group rows [wv*16, wv*16+16); coalesced per row
    {
        unsigned int pk = 0xFFFFFFFFu;
        #pragma unroll
        for (int s = wv * 16; s < wv * 16 + 16; ++s) {
            const unsigned int ub0 = __float_as_uint(slot[(size_t)s * total + g]);
            const unsigned int ub  = ((int)ub0 < 0) ? ~ub0 : (ub0 | 0x80000000u);
            pk = min(pk, (ub & 0xFFFFFFC0u) | (unsigned int)s);
        }
        atomicMin(&smin[lane], pk);                        // LDS; ties -> low group
    }
    __syncthreads();
    const int gr = (int)(smin[lane] & 63u);

    // A2: 4 workers/query, 32 exact targets each, 8 per step via named float4
    const float qx = q[3 * (g - bz * N)], qy = q[3 * (g - bz * N) + 1],
                qz = q[3 * (g - bz * N) + 2];
    {
        const float4* __restrict__ tb4 =
            (const float4*)(t + (size_t)gr * GRP * 3) + wv * 24;
        unsigned int best = 0xFFFFFFFFu;
        #pragma unroll
        for (int c = 0; c < 4; ++c) {                      // 4 x 8 targets
            const float4 v0 = tb4[c * 6 + 0];
            const float4 v1 = tb4[c * 6 + 1];
            const float4 v2 = tb4[c * 6 + 2];
            const float4 v3 = tb4[c * 6 + 3];
            const float4 v4 = tb4[c * 6 + 4];
            const float4 v5 = tb4[c * 6 + 5];
            DIST8(v0, v1, v2, v3, v4, v5, wv * 32 + c * 8);
        }
        atomicMin(&skey[lane], best);                      // LDS; first-min idx7
    }
    __syncthreads();

    unsigned int key = 0; int idxg = 0;
    if (tid < FQ) {
        key  = skey[tid];
        idxg = gr * GRP + (int)(key & 127u);               // global NN index
        atomicAdd(&cnt[bz * N + idxg], 1);
    }

    // grid barrier: 1024 blocks, 4/CU vs capacity >=6/CU -> deadlock-free spin
    __threadfence();
    __syncthreads();
    if (tid == 0) {
        __hip_atomic_fetch_add(arrive, 1, __ATOMIC_ACQ_REL, __HIP_MEMORY_SCOPE_AGENT);
        while (__hip_atomic_load(arrive, __ATOMIC_ACQUIRE, __HIP_MEMORY_SCOPE_AGENT)
               < (int)gridDim.x)
            __builtin_amdgcn_s_sleep(8);
    }
    __syncthreads();

    // B: loss. d from key high bits (<=2^-17 rel trunc of exact d) + final cnt
    if (tid < FQ) {
        const float d = __uint_as_float(key & 0xFFFFFF80u);
        const int   c = __hip_atomic_load(&cnt[bz * N + idxg], __ATOMIC_RELAXED,
                                          __HIP_MEMORY_SCOPE_AGENT);
        float sv = 1.0f - expf(-d) / ((float)c + 1e-6f);   // count^1, frac = 1
        #pragma unroll
        for (int off = 32; off > 0; off >>= 1) sv += __shfl_down(sv, off, 64);
        if (tid == 0)
            atomicAdd(&out[b], sv / (2.0f * (float)N));    // (mean1+mean2)/2
    }
}

extern "C" void kernel_launch(void* const* d_in, const int* in_sizes, int n_in,
                              void* d_out, int out_size, void* d_ws, size_t ws_size,
                              hipStream_t stream)
{
    const float* gts   = (const float*)d_in[0];
    const float* preds = (const float*)d_in[1];

    const int N = NPTS;
    const int B = in_sizes[0] / (N * 3);                   // = 4

    const size_t nTot = (size_t)2 * B * N;                 // 65536 queries
    float* slot   = (float*)d_ws;                          // NGRP x nTot (16.8MB)
    int*   cnt    = (int*)((char*)d_ws + (size_t)NGRP * nTot * sizeof(float));
    int*   arrive = cnt + nTot;

    dim3 gA(QCH, NSLICE, 2 * B);                           // 64 x 4 x 8 = 2048 blocks
    dacl_partial<<<gA, BLK, 0, stream>>>(gts, preds, slot, cnt, arrive, B, N);

    dacl_final<<<(int)(nTot / FQ), BLK, 0, stream>>>(      // 1024 blocks
        gts, preds, slot, cnt, arrive, (float*)d_out, out_size, B, N);
}

// Round 14
// 127.149 us; speedup vs baseline: 2.4452x; 2.4452x over previous
//
#include <hip/hip_runtime.h>
#include <math.h>

// Density-Aware Chamfer Loss, B=4, N=8192, fp32 3D points.
//
// Round-14: partial (MFMA, 45us, absmax 0.0) UNCHANGED. r13's homemade
// agent-scope spin barrier measured ~0.23us PER BLOCK (256 blk -> ~60us in
// r12, 1024 blk -> ~233us in r13) — strictly worse than a ~15us dispatch
// boundary. So: split at the barrier into two plain dispatches.
//   dacl_merge (1024 blocks, 4 workers/query): r13's proven A1+A2 —
//     A1: per-wave coalesced scan of 16 group rows, LDS atomicMin on
//         key = monotone(bits)&~0x3F | group  (ties -> lowest group)
//     A2: each worker rescans 32 targets of the winning group with EXACT
//         distances via named float4 (no indexable array -> no scratch),
//         LDS atomicMin on key = bits(d)&~0x7F | idx7 (first-min, jnp.argmin)
//     writes d -> slot row 0, idxg -> slot row 1 (slot rows are dead after A1;
//     per-query addresses are disjoint across blocks -> race-free reuse),
//     atomicAdd cnt histogram.
//   dacl_loss: per-query d/idx/cnt read, wave reduce, atomicAdd out[b]/(2N).
//
// ws: [slot 64grp x 2BN f32 (16.8MB)][cnt 2BN int]
// Dispatches: partial(+zero cnt) -> merge(+zero out) -> loss.   (3 total)

#define NPTS   8192
#define BLK    256
#define QPB    128                  // queries per block (partial; 4 waves x 32)
#define TPS    2048                 // targets per slice
#define TILES  (TPS / 32)           // 64 MFMA tiles per slice
#define NSLICE (NPTS / TPS)         // 4
#define QCH    (NPTS / QPB)         // 64
#define GRP    128                  // targets per slot group
#define NGRP   (NPTS / GRP)         // 64
#define FQ     64                   // queries per merge block

typedef __attribute__((ext_vector_type(8)))  short short8;
typedef __attribute__((ext_vector_type(16))) float float16v;

__device__ inline void bsplit(float x, unsigned short& h, unsigned short& l) {
    const unsigned int u = __float_as_uint(x);
    const unsigned short hh = (unsigned short)(u >> 16);   // truncated bf16 hi
    const float lf = x - __uint_as_float((unsigned int)hh << 16);
    h = hh;
    l = (unsigned short)(__float_as_uint(lf) >> 16);       // bf16 lo
}

__global__ __launch_bounds__(BLK) void dacl_partial(
    const float* __restrict__ gts, const float* __restrict__ preds,
    float* __restrict__ slot, int* __restrict__ cnt, int B, int N)
{
    const int bz  = blockIdx.z;      // dir*B + b
    const int dir = bz / B;
    const int b   = bz - dir * B;
    const int total = 2 * B * N;

    // fold cnt zeroing in (first read by dacl_merge -> boundary orders)
    if (blockIdx.y == 0) {
        const int per = total / (QCH * 2 * B);             // 128
        int* p = cnt + (blockIdx.x + QCH * bz) * per;
        for (int k = threadIdx.x; k < per; k += BLK) p[k] = 0;
    }

    const float* __restrict__ q = (dir == 0 ? gts : preds) + (size_t)b * N * 3;
    const float* __restrict__ t = (dir == 0 ? preds : gts) + (size_t)b * N * 3;

    __shared__ short8 frag[TILES * 64];                    // 64KB A-frags

    // stage+pack A-frags: 2048 targets, 8 per thread.  MFMA K=13 layout:
    // k0-2 thi.(-2qhi)  k3-5 thi.(-2qlo)  k6-8 tlo.(-2qhi)
    // k9 |t|^2hi.1  k10 |t|^2lo.1  k11 1.|q|^2hi  k12 1.|q|^2lo
    const int sbase = blockIdx.y * TPS;
    for (int rep = 0; rep < TPS / BLK; ++rep) {
        const int tgt = rep * BLK + threadIdx.x;
        const int j   = sbase + tgt;
        const float tx = t[3 * j], ty = t[3 * j + 1], tz = t[3 * j + 2];
        const float t2 = fmaf(tx, tx, fmaf(ty, ty, tz * tz));
        unsigned short hx, lx, hy, ly, hz, lz, h2, l2;
        bsplit(tx, hx, lx); bsplit(ty, hy, ly); bsplit(tz, hz, lz); bsplit(t2, h2, l2);
        union { short8 v; unsigned short s[8]; } k0, k1;
        k0.s[0]=hx; k0.s[1]=hy; k0.s[2]=hz; k0.s[3]=hx; k0.s[4]=hy; k0.s[5]=hz; k0.s[6]=lx; k0.s[7]=ly;
        k1.s[0]=lz; k1.s[1]=h2; k1.s[2]=l2; k1.s[3]=0x3F80; k1.s[4]=0x3F80; k1.s[5]=0; k1.s[6]=0; k1.s[7]=0;
        const int tile = tgt >> 5, row = tgt & 31;
        frag[tile * 64 + row]      = k0.v;                 // k-half 0 (lanes 0-31)
        frag[tile * 64 + 32 + row] = k1.v;                 // k-half 1 (lanes 32-63)
    }

    // B-frag: each wave owns 32 queries; lane&31 = query col (HW-verified
    // col=lane&31, m74/m101), lane>>5 = k-half
    const int lane = threadIdx.x & 63;
    const int wave = threadIdx.x >> 6;
    const int qi   = blockIdx.x * QPB + wave * 32 + (lane & 31);
    const float qx = q[3 * qi], qy = q[3 * qi + 1], qz = q[3 * qi + 2];
    const float q2 = fmaf(qx, qx, fmaf(qy, qy, qz * qz));
    unsigned short shx, slx, shy, sly, shz, slz, h2q, l2q;
    bsplit(-2.0f * qx, shx, slx); bsplit(-2.0f * qy, shy, sly);
    bsplit(-2.0f * qz, shz, slz); bsplit(q2, h2q, l2q);
    union { short8 v; unsigned short s[8]; } bu;
    if ((lane >> 5) == 0) {
        bu.s[0]=shx; bu.s[1]=shy; bu.s[2]=shz; bu.s[3]=slx; bu.s[4]=sly; bu.s[5]=slz; bu.s[6]=shx; bu.s[7]=shy;
    } else {
        bu.s[0]=shz; bu.s[1]=0x3F80; bu.s[2]=0x3F80; bu.s[3]=h2q; bu.s[4]=l2q; bu.s[5]=0; bu.s[6]=0; bu.s[7]=0;
    }
    const short8 bfrag = bu.v;

    __syncthreads();

    const float16v zz = {0.f,0.f,0.f,0.f, 0.f,0.f,0.f,0.f,
                         0.f,0.f,0.f,0.f, 0.f,0.f,0.f,0.f};
    const size_t gq = (size_t)bz * N + qi;
    float gmin = 3.402823466e38f;

    // hot loop: 1 ds_read_b128 + 1 mfma + 9-op min3 tree per 1024 pairs.
    // group-min is invariant to the C/D row permutation.
    #pragma unroll 2
    for (int tile = 0; tile < TILES; ++tile) {
        const short8 av = frag[tile * 64 + lane];
        float16v acc = __builtin_amdgcn_mfma_f32_32x32x16_bf16(av, bfrag, zz, 0, 0, 0);
        const float t0 = fminf(fminf(acc[0],  acc[1]),  acc[2]);
        const float t1 = fminf(fminf(acc[3],  acc[4]),  acc[5]);
        const float t2 = fminf(fminf(acc[6],  acc[7]),  acc[8]);
        const float t3 = fminf(fminf(acc[9],  acc[10]), acc[11]);
        const float t4 = fminf(fminf(acc[12], acc[13]), acc[14]);
        const float u0 = fminf(fminf(t0, t1), acc[15]);
        const float u1 = fminf(fminf(t2, t3), t4);
        gmin = fminf(gmin, fminf(u0, u1));
        if ((tile & 3) == 3) {                             // close a 128-target group
            const float o = fminf(gmin, __shfl_xor(gmin, 32, 64));  // both row-halves
            if (lane < 32)
                slot[(size_t)(blockIdx.y * (TILES / 4) + (tile >> 2)) * total + gq] = o;
            gmin = 3.402823466e38f;
        }
    }
}

__device__ inline float sq3(float x, float y, float z) {
    return fmaf(x, x, fmaf(y, y, z * z));
}

// 8 exact distances from 6 named float4 (12B per target) — no indexable array
#define DIST8(V0,V1,V2,V3,V4,V5,BASE)                                          \
    do {                                                                       \
        const float d0 = sq3(qx-(V0).x, qy-(V0).y, qz-(V0).z);                 \
        const float d1 = sq3(qx-(V0).w, qy-(V1).x, qz-(V1).y);                 \
        const float d2 = sq3(qx-(V1).z, qy-(V1).w, qz-(V2).x);                 \
        const float d3 = sq3(qx-(V2).y, qy-(V2).z, qz-(V2).w);                 \
        const float d4 = sq3(qx-(V3).x, qy-(V3).y, qz-(V3).z);                 \
        const float d5 = sq3(qx-(V3).w, qy-(V4).x, qz-(V4).y);                 \
        const float d6 = sq3(qx-(V4).z, qy-(V4).w, qz-(V5).x);                 \
        const float d7 = sq3(qx-(V5).y, qy-(V5).z, qz-(V5).w);                 \
        best = min(best, (__float_as_uint(d0) & 0xFFFFFF80u) | (unsigned)((BASE)+0)); \
        best = min(best, (__float_as_uint(d1) & 0xFFFFFF80u) | (unsigned)((BASE)+1)); \
        best = min(best, (__float_as_uint(d2) & 0xFFFFFF80u) | (unsigned)((BASE)+2)); \
        best = min(best, (__float_as_uint(d3) & 0xFFFFFF80u) | (unsigned)((BASE)+3)); \
        best = min(best, (__float_as_uint(d4) & 0xFFFFFF80u) | (unsigned)((BASE)+4)); \
        best = min(best, (__float_as_uint(d5) & 0xFFFFFF80u) | (unsigned)((BASE)+5)); \
        best = min(best, (__float_as_uint(d6) & 0xFFFFFF80u) | (unsigned)((BASE)+6)); \
        best = min(best, (__float_as_uint(d7) & 0xFFFFFF80u) | (unsigned)((BASE)+7)); \
    } while (0)

// A1 + A2 + count; 1024 blocks, 4 workers/query, NO barrier.
// Result reuse: d -> slot row 0, idxg -> slot row 1 (rows dead after A1;
// per-query addresses disjoint across blocks).
__global__ __launch_bounds__(BLK) void dacl_merge(
    const float* __restrict__ gts, const float* __restrict__ preds,
    float* __restrict__ slot, int* __restrict__ cnt,
    float* __restrict__ out, int out_size, int B, int N)
{
    const int tid  = threadIdx.x;
    const int lane = tid & 63;       // local query 0..63
    const int wv   = tid >> 6;       // sub-worker 0..3
    const int total = 2 * B * N;
    const int g0   = blockIdx.x * FQ;                      // first query of block
    const int bz   = g0 / N;                               // block-uniform
    const int dir  = bz / B;
    const int b    = bz - dir * B;
    const float* __restrict__ q = (dir == 0 ? gts : preds) + (size_t)b * N * 3;
    const float* __restrict__ t = (dir == 0 ? preds : gts) + (size_t)b * N * 3;

    __shared__ unsigned int smin[FQ];   // A1: trunc-monotone | group
    __shared__ unsigned int skey[FQ];   // A2: bits(d)&~0x7F | idx7

    if (blockIdx.x == 0 && tid < out_size) out[tid] = 0.0f;
    if (tid < FQ) { smin[tid] = 0xFFFFFFFFu; skey[tid] = 0xFFFFFFFFu; }
    __syncthreads();

    const int g = g0 + lane;                               // this query id

    // A1: wave wv scans group rows [wv*16, wv*16+16); coalesced per row
    {
        unsigned int pk = 0xFFFFFFFFu;
        #pragma unroll
        for (int s = wv * 16; s < wv * 16 + 16; ++s) {
            const unsigned int ub0 = __float_as_uint(slot[(size_t)s * total + g]);
            const unsigned int ub  = ((int)ub0 < 0) ? ~ub0 : (ub0 | 0x80000000u);
            pk = min(pk, (ub & 0xFFFFFFC0u) | (unsigned int)s);
        }
        atomicMin(&smin[lane], pk);                        // LDS; ties -> low group
    }
    __syncthreads();
    const int gr = (int)(smin[lane] & 63u);

    // A2: 4 workers/query, 32 exact targets each, 8 per step via named float4
    const float qx = q[3 * (g - bz * N)], qy = q[3 * (g - bz * N) + 1],
                qz = q[3 * (g - bz * N) + 2];
    {
        const float4* __restrict__ tb4 =
            (const float4*)(t + (size_t)gr * GRP * 3) + wv * 24;
        unsigned int best = 0xFFFFFFFFu;
        #pragma unroll
        for (int c = 0; c < 4; ++c) {                      // 4 x 8 targets
            const float4 v0 = tb4[c * 6 + 0];
            const float4 v1 = tb4[c * 6 + 1];
            const float4 v2 = tb4[c * 6 + 2];
            const float4 v3 = tb4[c * 6 + 3];
            const float4 v4 = tb4[c * 6 + 4];
            const float4 v5 = tb4[c * 6 + 5];
            DIST8(v0, v1, v2, v3, v4, v5, wv * 32 + c * 8);
        }
        atomicMin(&skey[lane], best);                      // LDS; first-min idx7
    }
    __syncthreads();

    if (tid < FQ) {
        const unsigned int key = skey[tid];
        const int idxg = (int)(smin[tid] & 63u) * GRP + (int)(key & 127u);
        slot[g0 + tid]                    = __uint_as_float(key & 0xFFFFFF80u); // d
        ((int*)slot)[total + g0 + tid]    = idxg;                               // idx
        atomicAdd(&cnt[bz * N + idxg], 1);
    }
}

__global__ __launch_bounds__(256) void dacl_loss(
    const float* __restrict__ slot, const int* __restrict__ cnt,
    float* __restrict__ out, int B, int N)
{
    const int g  = blockIdx.x * 256 + threadIdx.x;         // query id
    const int total = 2 * B * N;
    const int bz = g / N;
    const int b  = bz - (bz / B) * B;

    const float d   = slot[g];                             // exact (<=2^-17 trunc)
    const int   idx = ((const int*)slot)[total + g];
    const float c   = (float)cnt[bz * N + idx];            // count^1 (lambda=1)
    float sv = 1.0f - expf(-d) / (c + 1e-6f);              // frac terms = 1
    #pragma unroll
    for (int off = 32; off > 0; off >>= 1) sv += __shfl_down(sv, off, 64);
    if ((threadIdx.x & 63) == 0)
        atomicAdd(&out[b], sv / (2.0f * (float)N));        // (mean1+mean2)/2
}

extern "C" void kernel_launch(void* const* d_in, const int* in_sizes, int n_in,
                              void* d_out, int out_size, void* d_ws, size_t ws_size,
                              hipStream_t stream)
{
    const float* gts   = (const float*)d_in[0];
    const float* preds = (const float*)d_in[1];

    const int N = NPTS;
    const int B = in_sizes[0] / (N * 3);                   // = 4

    const size_t nTot = (size_t)2 * B * N;                 // 65536 queries
    float* slot = (float*)d_ws;                            // NGRP x nTot (16.8MB)
    int*   cnt  = (int*)((char*)d_ws + (size_t)NGRP * nTot * sizeof(float));

    dim3 gA(QCH, NSLICE, 2 * B);                           // 64 x 4 x 8 = 2048 blocks
    dacl_partial<<<gA, BLK, 0, stream>>>(gts, preds, slot, cnt, B, N);

    dacl_merge<<<(int)(nTot / FQ), BLK, 0, stream>>>(      // 1024 blocks
        gts, preds, slot, cnt, (float*)d_out, out_size, B, N);

    dacl_loss<<<(int)(nTot / 256), 256, 0, stream>>>(      // 256 blocks
        slot, cnt, (float*)d_out, B, N);
}

// Round 15
// 123.106 us; speedup vs baseline: 2.5255x; 1.0328x over previous
//
#include <hip/hip_runtime.h>
#include <math.h>

// Density-Aware Chamfer Loss, B=4, N=8192, fp32 3D points.
//
// Round-15: one variable vs r14 — TPS 2048 -> 1024 (LDS A-frags 64KB -> 32KB).
// r14's partial was residency-capped by LDS: 64KB/block -> 2 blocks/CU = 8
// waves/CU (Occupancy 17.5%), leaving MFMA->min-tree latency and the staging
// barrier uncovered (46us vs ~10us pipe floor). 32KB -> 5 blocks/CU = 20
// waves/CU. Total MFMA count, staging bytes, and the 64x128-target group
// structure (8 slices x 8 groups) are unchanged -> merge/loss logic identical.
//
// Pipeline (3 dispatches, no spin barriers — r13 measured the agent-scope spin
// at ~0.23us/block; a ~15us kernel boundary is strictly better):
//   partial: MFMA 32x32x16 bf16 hi/lo-split distance tiles (K=13 of 16),
//            9-op min3 tree, per-128-target-group f32 mins -> slot rows
//   merge:   A1 coalesced scan of 64 group rows (ties -> lowest group);
//            A2 exact rescan of the winning group, 4 workers/query, named
//            float4 (no indexable array); d/idx -> dead slot rows; cnt hist
//   loss:    per-query d/idx/cnt -> wave-reduce -> out[b]/(2N)
//
// ws: [slot 64grp x 2BN f32 (16.8MB)][cnt 2BN int]

#define NPTS   8192
#define BLK    256
#define QPB    128                  // queries per block (partial; 4 waves x 32)
#define TPS    1024                 // targets per slice (32KB LDS A-frags)
#define TILES  (TPS / 32)           // 32 MFMA tiles per slice
#define NSLICE (NPTS / TPS)         // 8
#define QCH    (NPTS / QPB)         // 64
#define GRP    128                  // targets per slot group
#define NGRP   (NPTS / GRP)         // 64
#define FQ     64                   // queries per merge block

typedef __attribute__((ext_vector_type(8)))  short short8;
typedef __attribute__((ext_vector_type(16))) float float16v;

__device__ inline void bsplit(float x, unsigned short& h, unsigned short& l) {
    const unsigned int u = __float_as_uint(x);
    const unsigned short hh = (unsigned short)(u >> 16);   // truncated bf16 hi
    const float lf = x - __uint_as_float((unsigned int)hh << 16);
    h = hh;
    l = (unsigned short)(__float_as_uint(lf) >> 16);       // bf16 lo
}

__global__ __launch_bounds__(BLK) void dacl_partial(
    const float* __restrict__ gts, const float* __restrict__ preds,
    float* __restrict__ slot, int* __restrict__ cnt, int B, int N)
{
    const int bz  = blockIdx.z;      // dir*B + b
    const int dir = bz / B;
    const int b   = bz - dir * B;
    const int total = 2 * B * N;

    // fold cnt zeroing in (first read by dacl_merge -> boundary orders)
    if (blockIdx.y == 0) {
        const int per = total / (QCH * 2 * B);             // 128
        int* p = cnt + (blockIdx.x + QCH * bz) * per;
        for (int k = threadIdx.x; k < per; k += BLK) p[k] = 0;
    }

    const float* __restrict__ q = (dir == 0 ? gts : preds) + (size_t)b * N * 3;
    const float* __restrict__ t = (dir == 0 ? preds : gts) + (size_t)b * N * 3;

    __shared__ short8 frag[TILES * 64];                    // 32KB A-frags

    // stage+pack A-frags: 1024 targets, 4 per thread.  MFMA K=13 layout:
    // k0-2 thi.(-2qhi)  k3-5 thi.(-2qlo)  k6-8 tlo.(-2qhi)
    // k9 |t|^2hi.1  k10 |t|^2lo.1  k11 1.|q|^2hi  k12 1.|q|^2lo
    const int sbase = blockIdx.y * TPS;
    for (int rep = 0; rep < TPS / BLK; ++rep) {
        const int tgt = rep * BLK + threadIdx.x;
        const int j   = sbase + tgt;
        const float tx = t[3 * j], ty = t[3 * j + 1], tz = t[3 * j + 2];
        const float t2 = fmaf(tx, tx, fmaf(ty, ty, tz * tz));
        unsigned short hx, lx, hy, ly, hz, lz, h2, l2;
        bsplit(tx, hx, lx); bsplit(ty, hy, ly); bsplit(tz, hz, lz); bsplit(t2, h2, l2);
        union { short8 v; unsigned short s[8]; } k0, k1;
        k0.s[0]=hx; k0.s[1]=hy; k0.s[2]=hz; k0.s[3]=hx; k0.s[4]=hy; k0.s[5]=hz; k0.s[6]=lx; k0.s[7]=ly;
        k1.s[0]=lz; k1.s[1]=h2; k1.s[2]=l2; k1.s[3]=0x3F80; k1.s[4]=0x3F80; k1.s[5]=0; k1.s[6]=0; k1.s[7]=0;
        const int tile = tgt >> 5, row = tgt & 31;
        frag[tile * 64 + row]      = k0.v;                 // k-half 0 (lanes 0-31)
        frag[tile * 64 + 32 + row] = k1.v;                 // k-half 1 (lanes 32-63)
    }

    // B-frag: each wave owns 32 queries; lane&31 = query col (HW-verified
    // col=lane&31, m74/m101), lane>>5 = k-half
    const int lane = threadIdx.x & 63;
    const int wave = threadIdx.x >> 6;
    const int qi   = blockIdx.x * QPB + wave * 32 + (lane & 31);
    const float qx = q[3 * qi], qy = q[3 * qi + 1], qz = q[3 * qi + 2];
    const float q2 = fmaf(qx, qx, fmaf(qy, qy, qz * qz));
    unsigned short shx, slx, shy, sly, shz, slz, h2q, l2q;
    bsplit(-2.0f * qx, shx, slx); bsplit(-2.0f * qy, shy, sly);
    bsplit(-2.0f * qz, shz, slz); bsplit(q2, h2q, l2q);
    union { short8 v; unsigned short s[8]; } bu;
    if ((lane >> 5) == 0) {
        bu.s[0]=shx; bu.s[1]=shy; bu.s[2]=shz; bu.s[3]=slx; bu.s[4]=sly; bu.s[5]=slz; bu.s[6]=shx; bu.s[7]=shy;
    } else {
        bu.s[0]=shz; bu.s[1]=0x3F80; bu.s[2]=0x3F80; bu.s[3]=h2q; bu.s[4]=l2q; bu.s[5]=0; bu.s[6]=0; bu.s[7]=0;
    }
    const short8 bfrag = bu.v;

    __syncthreads();

    const float16v zz = {0.f,0.f,0.f,0.f, 0.f,0.f,0.f,0.f,
                         0.f,0.f,0.f,0.f, 0.f,0.f,0.f,0.f};
    const size_t gq = (size_t)bz * N + qi;
    float gmin = 3.402823466e38f;

    // hot loop: 1 ds_read_b128 + 1 mfma + 9-op min3 tree per 1024 pairs.
    // group-min is invariant to the C/D row permutation.
    #pragma unroll 2
    for (int tile = 0; tile < TILES; ++tile) {
        const short8 av = frag[tile * 64 + lane];
        float16v acc = __builtin_amdgcn_mfma_f32_32x32x16_bf16(av, bfrag, zz, 0, 0, 0);
        const float t0 = fminf(fminf(acc[0],  acc[1]),  acc[2]);
        const float t1 = fminf(fminf(acc[3],  acc[4]),  acc[5]);
        const float t2 = fminf(fminf(acc[6],  acc[7]),  acc[8]);
        const float t3 = fminf(fminf(acc[9],  acc[10]), acc[11]);
        const float t4 = fminf(fminf(acc[12], acc[13]), acc[14]);
        const float u0 = fminf(fminf(t0, t1), acc[15]);
        const float u1 = fminf(fminf(t2, t3), t4);
        gmin = fminf(gmin, fminf(u0, u1));
        if ((tile & 3) == 3) {                             // close a 128-target group
            const float o = fminf(gmin, __shfl_xor(gmin, 32, 64));  // both row-halves
            if (lane < 32)
                slot[(size_t)(blockIdx.y * (TILES / 4) + (tile >> 2)) * total + gq] = o;
            gmin = 3.402823466e38f;
        }
    }
}

__device__ inline float sq3(float x, float y, float z) {
    return fmaf(x, x, fmaf(y, y, z * z));
}

// 8 exact distances from 6 named float4 (12B per target) — no indexable array
#define DIST8(V0,V1,V2,V3,V4,V5,BASE)                                          \
    do {                                                                       \
        const float d0 = sq3(qx-(V0).x, qy-(V0).y, qz-(V0).z);                 \
        const float d1 = sq3(qx-(V0).w, qy-(V1).x, qz-(V1).y);                 \
        const float d2 = sq3(qx-(V1).z, qy-(V1).w, qz-(V2).x);                 \
        const float d3 = sq3(qx-(V2).y, qy-(V2).z, qz-(V2).w);                 \
        const float d4 = sq3(qx-(V3).x, qy-(V3).y, qz-(V3).z);                 \
        const float d5 = sq3(qx-(V3).w, qy-(V4).x, qz-(V4).y);                 \
        const float d6 = sq3(qx-(V4).z, qy-(V4).w, qz-(V5).x);                 \
        const float d7 = sq3(qx-(V5).y, qy-(V5).z, qz-(V5).w);                 \
        best = min(best, (__float_as_uint(d0) & 0xFFFFFF80u) | (unsigned)((BASE)+0)); \
        best = min(best, (__float_as_uint(d1) & 0xFFFFFF80u) | (unsigned)((BASE)+1)); \
        best = min(best, (__float_as_uint(d2) & 0xFFFFFF80u) | (unsigned)((BASE)+2)); \
        best = min(best, (__float_as_uint(d3) & 0xFFFFFF80u) | (unsigned)((BASE)+3)); \
        best = min(best, (__float_as_uint(d4) & 0xFFFFFF80u) | (unsigned)((BASE)+4)); \
        best = min(best, (__float_as_uint(d5) & 0xFFFFFF80u) | (unsigned)((BASE)+5)); \
        best = min(best, (__float_as_uint(d6) & 0xFFFFFF80u) | (unsigned)((BASE)+6)); \
        best = min(best, (__float_as_uint(d7) & 0xFFFFFF80u) | (unsigned)((BASE)+7)); \
    } while (0)

// A1 + A2 + count; 1024 blocks, 4 workers/query, NO barrier.
// Result reuse: d -> slot row 0, idxg -> slot row 1 (rows dead after A1;
// per-query addresses disjoint across blocks).
__global__ __launch_bounds__(BLK) void dacl_merge(
    const float* __restrict__ gts, const float* __restrict__ preds,
    float* __restrict__ slot, int* __restrict__ cnt,
    float* __restrict__ out, int out_size, int B, int N)
{
    const int tid  = threadIdx.x;
    const int lane = tid & 63;       // local query 0..63
    const int wv   = tid >> 6;       // sub-worker 0..3
    const int total = 2 * B * N;
    const int g0   = blockIdx.x * FQ;                      // first query of block
    const int bz   = g0 / N;                               // block-uniform
    const int dir  = bz / B;
    const int b    = bz - dir * B;
    const float* __restrict__ q = (dir == 0 ? gts : preds) + (size_t)b * N * 3;
    const float* __restrict__ t = (dir == 0 ? preds : gts) + (size_t)b * N * 3;

    __shared__ unsigned int smin[FQ];   // A1: trunc-monotone | group
    __shared__ unsigned int skey[FQ];   // A2: bits(d)&~0x7F | idx7

    if (blockIdx.x == 0 && tid < out_size) out[tid] = 0.0f;
    if (tid < FQ) { smin[tid] = 0xFFFFFFFFu; skey[tid] = 0xFFFFFFFFu; }
    __syncthreads();

    const int g = g0 + lane;                               // this query id

    // A1: wave wv scans group rows [wv*16, wv*16+16); coalesced per row
    {
        unsigned int pk = 0xFFFFFFFFu;
        #pragma unroll
        for (int s = wv * 16; s < wv * 16 + 16; ++s) {
            const unsigned int ub0 = __float_as_uint(slot[(size_t)s * total + g]);
            const unsigned int ub  = ((int)ub0 < 0) ? ~ub0 : (ub0 | 0x80000000u);
            pk = min(pk, (ub & 0xFFFFFFC0u) | (unsigned int)s);
        }
        atomicMin(&smin[lane], pk);                        // LDS; ties -> low group
    }
    __syncthreads();
    const int gr = (int)(smin[lane] & 63u);

    // A2: 4 workers/query, 32 exact targets each, 8 per step via named float4
    const float qx = q[3 * (g - bz * N)], qy = q[3 * (g - bz * N) + 1],
                qz = q[3 * (g - bz * N) + 2];
    {
        const float4* __restrict__ tb4 =
            (const float4*)(t + (size_t)gr * GRP * 3) + wv * 24;
        unsigned int best = 0xFFFFFFFFu;
        #pragma unroll
        for (int c = 0; c < 4; ++c) {                      // 4 x 8 targets
            const float4 v0 = tb4[c * 6 + 0];
            const float4 v1 = tb4[c * 6 + 1];
            const float4 v2 = tb4[c * 6 + 2];
            const float4 v3 = tb4[c * 6 + 3];
            const float4 v4 = tb4[c * 6 + 4];
            const float4 v5 = tb4[c * 6 + 5];
            DIST8(v0, v1, v2, v3, v4, v5, wv * 32 + c * 8);
        }
        atomicMin(&skey[lane], best);                      // LDS; first-min idx7
    }
    __syncthreads();

    if (tid < FQ) {
        const unsigned int key = skey[tid];
        const int idxg = (int)(smin[tid] & 63u) * GRP + (int)(key & 127u);
        slot[g0 + tid]                    = __uint_as_float(key & 0xFFFFFF80u); // d
        ((int*)slot)[total + g0 + tid]    = idxg;                               // idx
        atomicAdd(&cnt[bz * N + idxg], 1);
    }
}

__global__ __launch_bounds__(256) void dacl_loss(
    const float* __restrict__ slot, const int* __restrict__ cnt,
    float* __restrict__ out, int B, int N)
{
    const int g  = blockIdx.x * 256 + threadIdx.x;         // query id
    const int total = 2 * B * N;
    const int bz = g / N;
    const int b  = bz - (bz / B) * B;

    const float d   = slot[g];                             // exact (<=2^-17 trunc)
    const int   idx = ((const int*)slot)[total + g];
    const float c   = (float)cnt[bz * N + idx];            // count^1 (lambda=1)
    float sv = 1.0f - expf(-d) / (c + 1e-6f);              // frac terms = 1
    #pragma unroll
    for (int off = 32; off > 0; off >>= 1) sv += __shfl_down(sv, off, 64);
    if ((threadIdx.x & 63) == 0)
        atomicAdd(&out[b], sv / (2.0f * (float)N));        // (mean1+mean2)/2
}

extern "C" void kernel_launch(void* const* d_in, const int* in_sizes, int n_in,
                              void* d_out, int out_size, void* d_ws, size_t ws_size,
                              hipStream_t stream)
{
    const float* gts   = (const float*)d_in[0];
    const float* preds = (const float*)d_in[1];

    const int N = NPTS;
    const int B = in_sizes[0] / (N * 3);                   // = 4

    const size_t nTot = (size_t)2 * B * N;                 // 65536 queries
    float* slot = (float*)d_ws;                            // NGRP x nTot (16.8MB)
    int*   cnt  = (int*)((char*)d_ws + (size_t)NGRP * nTot * sizeof(float));

    dim3 gA(QCH, NSLICE, 2 * B);                           // 64 x 8 x 8 = 4096 blocks
    dacl_partial<<<gA, BLK, 0, stream>>>(gts, preds, slot, cnt, B, N);

    dacl_merge<<<(int)(nTot / FQ), BLK, 0, stream>>>(      // 1024 blocks
        gts, preds, slot, cnt, (float*)d_out, out_size, B, N);

    dacl_loss<<<(int)(nTot / 256), 256, 0, stream>>>(      // 256 blocks
        slot, cnt, (float*)d_out, B, N);
}

// Round 16
// 116.242 us; speedup vs baseline: 2.6746x; 1.0590x over previous
//
#include <hip/hip_runtime.h>
#include <math.h>

// Density-Aware Chamfer Loss, B=4, N=8192, fp32 3D points.
//
// Round-16 vs r15 (123us, absmax 0.0):
//  (1) partial QPB 128->256: each wave carries TWO B-frags (query cols qi and
//      qi+128) -> 2 independent MFMA+min-tree chains per tile (2x ILP vs the
//      MFMA-result latency) and QCH 64->32 halves redundant slice staging.
//  (2) GRP 128->256 (NGRP=32): halves partial slot-write traffic (16.6->8.3MB)
//      and merge A1 row reads; A2 rescans 256 L2-resident targets with 4
//      workers x 64; idx8 packs in 8 bits (d trunc 2^-15 rel, validated
//      headroom: r8 passed at 2^-10).
// Structure otherwise unchanged: MFMA 32x32x16 bf16 hi/lo split (K=13 of 16),
// group-min invariant to C/D row permutation, exact-distance rescan for the
// index (first-min tie-break = jnp.argmin), exact d for the loss.
//
// ws: [slot 32grp x 2BN f32 (8.4MB)][cnt 2BN int]
// Dispatches: partial(+zero cnt) -> merge(+zero out) -> loss.   (3 total)

#define NPTS   8192
#define BLK    256
#define QPB    256                  // queries per block (partial; 4 waves x 2x32)
#define TPS    1024                 // targets per slice (32KB LDS A-frags)
#define TILES  (TPS / 32)           // 32 MFMA tiles per slice
#define NSLICE (NPTS / TPS)         // 8
#define QCH    (NPTS / QPB)         // 32
#define GRP    256                  // targets per slot group
#define NGRP   (NPTS / GRP)         // 32
#define FQ     64                   // queries per merge block

typedef __attribute__((ext_vector_type(8)))  short short8;
typedef __attribute__((ext_vector_type(16))) float float16v;

__device__ inline void bsplit(float x, unsigned short& h, unsigned short& l) {
    const unsigned int u = __float_as_uint(x);
    const unsigned short hh = (unsigned short)(u >> 16);   // truncated bf16 hi
    const float lf = x - __uint_as_float((unsigned int)hh << 16);
    h = hh;
    l = (unsigned short)(__float_as_uint(lf) >> 16);       // bf16 lo
}

__device__ inline short8 make_bfrag(float qx, float qy, float qz, int khalf) {
    const float q2 = fmaf(qx, qx, fmaf(qy, qy, qz * qz));
    unsigned short shx, slx, shy, sly, shz, slz, h2q, l2q;
    bsplit(-2.0f * qx, shx, slx); bsplit(-2.0f * qy, shy, sly);
    bsplit(-2.0f * qz, shz, slz); bsplit(q2, h2q, l2q);
    union { short8 v; unsigned short s[8]; } bu;
    if (khalf == 0) {
        bu.s[0]=shx; bu.s[1]=shy; bu.s[2]=shz; bu.s[3]=slx; bu.s[4]=sly; bu.s[5]=slz; bu.s[6]=shx; bu.s[7]=shy;
    } else {
        bu.s[0]=shz; bu.s[1]=0x3F80; bu.s[2]=0x3F80; bu.s[3]=h2q; bu.s[4]=l2q; bu.s[5]=0; bu.s[6]=0; bu.s[7]=0;
    }
    return bu.v;
}

__device__ inline float tree16(const float16v& a) {
    const float t0 = fminf(fminf(a[0],  a[1]),  a[2]);
    const float t1 = fminf(fminf(a[3],  a[4]),  a[5]);
    const float t2 = fminf(fminf(a[6],  a[7]),  a[8]);
    const float t3 = fminf(fminf(a[9],  a[10]), a[11]);
    const float t4 = fminf(fminf(a[12], a[13]), a[14]);
    return fminf(fminf(fminf(t0, t1), a[15]), fminf(fminf(t2, t3), t4));
}

__global__ __launch_bounds__(BLK, 4) void dacl_partial(
    const float* __restrict__ gts, const float* __restrict__ preds,
    float* __restrict__ slot, int* __restrict__ cnt, int B, int N)
{
    const int bz  = blockIdx.z;      // dir*B + b
    const int dir = bz / B;
    const int b   = bz - dir * B;
    const int total = 2 * B * N;

    // fold cnt zeroing in (first read by dacl_merge -> boundary orders)
    if (blockIdx.y == 0) {
        const int per = total / (QCH * 2 * B);             // 256
        int* p = cnt + (blockIdx.x + QCH * bz) * per;
        for (int k = threadIdx.x; k < per; k += BLK) p[k] = 0;
    }

    const float* __restrict__ q = (dir == 0 ? gts : preds) + (size_t)b * N * 3;
    const float* __restrict__ t = (dir == 0 ? preds : gts) + (size_t)b * N * 3;

    __shared__ short8 frag[TILES * 64];                    // 32KB A-frags

    // stage+pack A-frags: 1024 targets, 4 per thread.  MFMA K=13 layout:
    // k0-2 thi.(-2qhi)  k3-5 thi.(-2qlo)  k6-8 tlo.(-2qhi)
    // k9 |t|^2hi.1  k10 |t|^2lo.1  k11 1.|q|^2hi  k12 1.|q|^2lo
    const int sbase = blockIdx.y * TPS;
    for (int rep = 0; rep < TPS / BLK; ++rep) {
        const int tgt = rep * BLK + threadIdx.x;
        const int j   = sbase + tgt;
        const float tx = t[3 * j], ty = t[3 * j + 1], tz = t[3 * j + 2];
        const float t2 = fmaf(tx, tx, fmaf(ty, ty, tz * tz));
        unsigned short hx, lx, hy, ly, hz, lz, h2, l2;
        bsplit(tx, hx, lx); bsplit(ty, hy, ly); bsplit(tz, hz, lz); bsplit(t2, h2, l2);
        union { short8 v; unsigned short s[8]; } k0, k1;
        k0.s[0]=hx; k0.s[1]=hy; k0.s[2]=hz; k0.s[3]=hx; k0.s[4]=hy; k0.s[5]=hz; k0.s[6]=lx; k0.s[7]=ly;
        k1.s[0]=lz; k1.s[1]=h2; k1.s[2]=l2; k1.s[3]=0x3F80; k1.s[4]=0x3F80; k1.s[5]=0; k1.s[6]=0; k1.s[7]=0;
        const int tile = tgt >> 5, row = tgt & 31;
        frag[tile * 64 + row]      = k0.v;                 // k-half 0 (lanes 0-31)
        frag[tile * 64 + 32 + row] = k1.v;                 // k-half 1 (lanes 32-63)
    }

    // two B-frags per wave: query cols qiA and qiB = qiA+128
    // (col = lane&31, HW-verified m74/m101; lane>>5 = k-half)
    const int lane = threadIdx.x & 63;
    const int wave = threadIdx.x >> 6;
    const int qiA  = blockIdx.x * QPB + wave * 32 + (lane & 31);
    const int qiB  = qiA + 128;
    const short8 bfragA = make_bfrag(q[3*qiA], q[3*qiA+1], q[3*qiA+2], lane >> 5);
    const short8 bfragB = make_bfrag(q[3*qiB], q[3*qiB+1], q[3*qiB+2], lane >> 5);

    __syncthreads();

    const float16v zz = {0.f,0.f,0.f,0.f, 0.f,0.f,0.f,0.f,
                         0.f,0.f,0.f,0.f, 0.f,0.f,0.f,0.f};
    const size_t gqA = (size_t)bz * N + qiA;
    const size_t gqB = (size_t)bz * N + qiB;
    float gminA = 3.402823466e38f, gminB = 3.402823466e38f;

    // hot loop: 1 ds_read_b128 + 2 independent MFMA + 2 min3 trees per tile
    #pragma unroll 2
    for (int tile = 0; tile < TILES; ++tile) {
        const short8 av = frag[tile * 64 + lane];
        const float16v accA = __builtin_amdgcn_mfma_f32_32x32x16_bf16(av, bfragA, zz, 0, 0, 0);
        const float16v accB = __builtin_amdgcn_mfma_f32_32x32x16_bf16(av, bfragB, zz, 0, 0, 0);
        gminA = fminf(gminA, tree16(accA));
        gminB = fminf(gminB, tree16(accB));
        if ((tile & 7) == 7) {                             // close a 256-target group
            const size_t rbase =
                (size_t)(blockIdx.y * (TILES / 8) + (tile >> 3)) * total;
            const float oA = fminf(gminA, __shfl_xor(gminA, 32, 64));
            const float oB = fminf(gminB, __shfl_xor(gminB, 32, 64));
            if (lane < 32) {
                slot[rbase + gqA] = oA;
                slot[rbase + gqB] = oB;
            }
            gminA = 3.402823466e38f;
            gminB = 3.402823466e38f;
        }
    }
}

__device__ inline float sq3(float x, float y, float z) {
    return fmaf(x, x, fmaf(y, y, z * z));
}

// 8 exact distances from 6 named float4 (12B per target) — no indexable array
#define DIST8(V0,V1,V2,V3,V4,V5,BASE)                                          \
    do {                                                                       \
        const float d0 = sq3(qx-(V0).x, qy-(V0).y, qz-(V0).z);                 \
        const float d1 = sq3(qx-(V0).w, qy-(V1).x, qz-(V1).y);                 \
        const float d2 = sq3(qx-(V1).z, qy-(V1).w, qz-(V2).x);                 \
        const float d3 = sq3(qx-(V2).y, qy-(V2).z, qz-(V2).w);                 \
        const float d4 = sq3(qx-(V3).x, qy-(V3).y, qz-(V3).z);                 \
        const float d5 = sq3(qx-(V3).w, qy-(V4).x, qz-(V4).y);                 \
        const float d6 = sq3(qx-(V4).z, qy-(V4).w, qz-(V5).x);                 \
        const float d7 = sq3(qx-(V5).y, qy-(V5).z, qz-(V5).w);                 \
        best = min(best, (__float_as_uint(d0) & 0xFFFFFF00u) | (unsigned)((BASE)+0)); \
        best = min(best, (__float_as_uint(d1) & 0xFFFFFF00u) | (unsigned)((BASE)+1)); \
        best = min(best, (__float_as_uint(d2) & 0xFFFFFF00u) | (unsigned)((BASE)+2)); \
        best = min(best, (__float_as_uint(d3) & 0xFFFFFF00u) | (unsigned)((BASE)+3)); \
        best = min(best, (__float_as_uint(d4) & 0xFFFFFF00u) | (unsigned)((BASE)+4)); \
        best = min(best, (__float_as_uint(d5) & 0xFFFFFF00u) | (unsigned)((BASE)+5)); \
        best = min(best, (__float_as_uint(d6) & 0xFFFFFF00u) | (unsigned)((BASE)+6)); \
        best = min(best, (__float_as_uint(d7) & 0xFFFFFF00u) | (unsigned)((BASE)+7)); \
    } while (0)

// A1 + A2 + count; 1024 blocks, 4 workers/query, NO barrier (r13: spin costs
// ~0.23us/block — a dispatch boundary is strictly better).
// Result reuse: d -> slot row 0, idxg -> slot row 1 (rows dead after A1).
__global__ __launch_bounds__(BLK) void dacl_merge(
    const float* __restrict__ gts, const float* __restrict__ preds,
    float* __restrict__ slot, int* __restrict__ cnt,
    float* __restrict__ out, int out_size, int B, int N)
{
    const int tid  = threadIdx.x;
    const int lane = tid & 63;       // local query 0..63
    const int wv   = tid >> 6;       // sub-worker 0..3
    const int total = 2 * B * N;
    const int g0   = blockIdx.x * FQ;                      // first query of block
    const int bz   = g0 / N;                               // block-uniform
    const int dir  = bz / B;
    const int b    = bz - dir * B;
    const float* __restrict__ q = (dir == 0 ? gts : preds) + (size_t)b * N * 3;
    const float* __restrict__ t = (dir == 0 ? preds : gts) + (size_t)b * N * 3;

    __shared__ unsigned int smin[FQ];   // A1: trunc-monotone | group5
    __shared__ unsigned int skey[FQ];   // A2: bits(d)&~0xFF | idx8

    if (blockIdx.x == 0 && tid < out_size) out[tid] = 0.0f;
    if (tid < FQ) { smin[tid] = 0xFFFFFFFFu; skey[tid] = 0xFFFFFFFFu; }
    __syncthreads();

    const int g = g0 + lane;                               // this query id

    // A1: wave wv scans group rows [wv*8, wv*8+8); coalesced per row
    {
        unsigned int pk = 0xFFFFFFFFu;
        #pragma unroll
        for (int s = wv * 8; s < wv * 8 + 8; ++s) {
            const unsigned int ub0 = __float_as_uint(slot[(size_t)s * total + g]);
            const unsigned int ub  = ((int)ub0 < 0) ? ~ub0 : (ub0 | 0x80000000u);
            pk = min(pk, (ub & 0xFFFFFFE0u) | (unsigned int)s);
        }
        atomicMin(&smin[lane], pk);                        // LDS; ties -> low group
    }
    __syncthreads();
    const int gr = (int)(smin[lane] & 31u);

    // A2: 4 workers/query, 64 exact targets each, 8 per step via named float4
    const float qx = q[3 * (g - bz * N)], qy = q[3 * (g - bz * N) + 1],
                qz = q[3 * (g - bz * N) + 2];
    {
        const float4* __restrict__ tb4 =
            (const float4*)(t + (size_t)gr * GRP * 3) + wv * 48;
        unsigned int best = 0xFFFFFFFFu;
        #pragma unroll
        for (int c = 0; c < 8; ++c) {                      // 8 x 8 targets
            const float4 v0 = tb4[c * 6 + 0];
            const float4 v1 = tb4[c * 6 + 1];
            const float4 v2 = tb4[c * 6 + 2];
            const float4 v3 = tb4[c * 6 + 3];
            const float4 v4 = tb4[c * 6 + 4];
            const float4 v5 = tb4[c * 6 + 5];
            DIST8(v0, v1, v2, v3, v4, v5, wv * 64 + c * 8);
        }
        atomicMin(&skey[lane], best);                      // LDS; first-min idx8
    }
    __syncthreads();

    if (tid < FQ) {
        const unsigned int key = skey[tid];
        const int idxg = (int)(smin[tid] & 31u) * GRP + (int)(key & 255u);
        slot[g0 + tid]                 = __uint_as_float(key & 0xFFFFFF00u); // d
        ((int*)slot)[total + g0 + tid] = idxg;                               // idx
        atomicAdd(&cnt[bz * N + idxg], 1);
    }
}

__global__ __launch_bounds__(256) void dacl_loss(
    const float* __restrict__ slot, const int* __restrict__ cnt,
    float* __restrict__ out, int B, int N)
{
    const int g  = blockIdx.x * 256 + threadIdx.x;         // query id
    const int total = 2 * B * N;
    const int bz = g / N;
    const int b  = bz - (bz / B) * B;

    const float d   = slot[g];                             // exact (<=2^-15 trunc)
    const int   idx = ((const int*)slot)[total + g];
    const float c   = (float)cnt[bz * N + idx];            // count^1 (lambda=1)
    float sv = 1.0f - expf(-d) / (c + 1e-6f);              // frac terms = 1
    #pragma unroll
    for (int off = 32; off > 0; off >>= 1) sv += __shfl_down(sv, off, 64);
    if ((threadIdx.x & 63) == 0)
        atomicAdd(&out[b], sv / (2.0f * (float)N));        // (mean1+mean2)/2
}

extern "C" void kernel_launch(void* const* d_in, const int* in_sizes, int n_in,
                              void* d_out, int out_size, void* d_ws, size_t ws_size,
                              hipStream_t stream)
{
    const float* gts   = (const float*)d_in[0];
    const float* preds = (const float*)d_in[1];

    const int N = NPTS;
    const int B = in_sizes[0] / (N * 3);                   // = 4

    const size_t nTot = (size_t)2 * B * N;                 // 65536 queries
    float* slot = (float*)d_ws;                            // NGRP x nTot (8.4MB)
    int*   cnt  = (int*)((char*)d_ws + (size_t)NGRP * nTot * sizeof(float));

    dim3 gA(QCH, NSLICE, 2 * B);                           // 32 x 8 x 8 = 2048 blocks
    dacl_partial<<<gA, BLK, 0, stream>>>(gts, preds, slot, cnt, B, N);

    dacl_merge<<<(int)(nTot / FQ), BLK, 0, stream>>>(      // 1024 blocks
        gts, preds, slot, cnt, (float*)d_out, out_size, B, N);

    dacl_loss<<<(int)(nTot / 256), 256, 0, stream>>>(      // 256 blocks
        slot, cnt, (float*)d_out, B, N);
}

// Round 17
// 113.112 us; speedup vs baseline: 2.7486x; 1.0277x over previous
//
#include <hip/hip_runtime.h>
#include <math.h>

// Density-Aware Chamfer Loss, B=4, N=8192, fp32 3D points.
//
// Round-17 vs r16 (116us, absmax 0.0): ONE variable — QPB 256 -> 512.
// Each wave now carries FOUR B-frags (query cols qi, qi+128, qi+256, qi+384)
// -> 4 independent MFMA+min-tree chains per A-frag (4x ILP vs MFMA-result
// latency) and QCH 32 -> 16 halves the redundant per-slice staging/pack work.
// Grid 1024 blocks = 4/CU (unchanged residency: LDS 32KB allowed 5, VGPR
// bounds 4). Numerically identical to r16 -> absmax must stay 0.0.
//
// Structure: MFMA 32x32x16 bf16 hi/lo split (K=13 of 16) exact-form distance
// tiles; per-256-target-group f32 mins -> slot rows (group-min invariant to
// C/D row permutation; col=lane&31 HW-verified m74/m101); merge: A1 coalesced
// 32-row scan (ties -> lowest group) + A2 exact rescan, 4 workers/query,
// named float4 (no indexable array), first-min tie-break = jnp.argmin;
// loss: exact d (2^-15 trunc) + final cnt. No spin barriers (r13: 0.23us/blk).
//
// ws: [slot 32grp x 2BN f32 (8.4MB)][cnt 2BN int]
// Dispatches: partial(+zero cnt) -> merge(+zero out) -> loss.   (3 total)

#define NPTS   8192
#define BLK    256
#define QPB    512                  // queries per block (partial; 4 waves x 4x32)
#define TPS    1024                 // targets per slice (32KB LDS A-frags)
#define TILES  (TPS / 32)           // 32 MFMA tiles per slice
#define NSLICE (NPTS / TPS)         // 8
#define QCH    (NPTS / QPB)         // 16
#define GRP    256                  // targets per slot group
#define NGRP   (NPTS / GRP)         // 32
#define FQ     64                   // queries per merge block

typedef __attribute__((ext_vector_type(8)))  short short8;
typedef __attribute__((ext_vector_type(16))) float float16v;

__device__ inline void bsplit(float x, unsigned short& h, unsigned short& l) {
    const unsigned int u = __float_as_uint(x);
    const unsigned short hh = (unsigned short)(u >> 16);   // truncated bf16 hi
    const float lf = x - __uint_as_float((unsigned int)hh << 16);
    h = hh;
    l = (unsigned short)(__float_as_uint(lf) >> 16);       // bf16 lo
}

__device__ inline short8 make_bfrag(float qx, float qy, float qz, int khalf) {
    const float q2 = fmaf(qx, qx, fmaf(qy, qy, qz * qz));
    unsigned short shx, slx, shy, sly, shz, slz, h2q, l2q;
    bsplit(-2.0f * qx, shx, slx); bsplit(-2.0f * qy, shy, sly);
    bsplit(-2.0f * qz, shz, slz); bsplit(q2, h2q, l2q);
    union { short8 v; unsigned short s[8]; } bu;
    if (khalf == 0) {
        bu.s[0]=shx; bu.s[1]=shy; bu.s[2]=shz; bu.s[3]=slx; bu.s[4]=sly; bu.s[5]=slz; bu.s[6]=shx; bu.s[7]=shy;
    } else {
        bu.s[0]=shz; bu.s[1]=0x3F80; bu.s[2]=0x3F80; bu.s[3]=h2q; bu.s[4]=l2q; bu.s[5]=0; bu.s[6]=0; bu.s[7]=0;
    }
    return bu.v;
}

__device__ inline float tree16(const float16v& a) {
    const float t0 = fminf(fminf(a[0],  a[1]),  a[2]);
    const float t1 = fminf(fminf(a[3],  a[4]),  a[5]);
    const float t2 = fminf(fminf(a[6],  a[7]),  a[8]);
    const float t3 = fminf(fminf(a[9],  a[10]), a[11]);
    const float t4 = fminf(fminf(a[12], a[13]), a[14]);
    return fminf(fminf(fminf(t0, t1), a[15]), fminf(fminf(t2, t3), t4));
}

__global__ __launch_bounds__(BLK, 4) void dacl_partial(
    const float* __restrict__ gts, const float* __restrict__ preds,
    float* __restrict__ slot, int* __restrict__ cnt, int B, int N)
{
    const int bz  = blockIdx.z;      // dir*B + b
    const int dir = bz / B;
    const int b   = bz - dir * B;
    const int total = 2 * B * N;

    // fold cnt zeroing in (first read by dacl_merge -> boundary orders)
    if (blockIdx.y == 0) {
        const int per = total / (QCH * 2 * B);             // 512
        int* p = cnt + (blockIdx.x + QCH * bz) * per;
        for (int k = threadIdx.x; k < per; k += BLK) p[k] = 0;
    }

    const float* __restrict__ q = (dir == 0 ? gts : preds) + (size_t)b * N * 3;
    const float* __restrict__ t = (dir == 0 ? preds : gts) + (size_t)b * N * 3;

    __shared__ short8 frag[TILES * 64];                    // 32KB A-frags

    // stage+pack A-frags: 1024 targets, 4 per thread.  MFMA K=13 layout:
    // k0-2 thi.(-2qhi)  k3-5 thi.(-2qlo)  k6-8 tlo.(-2qhi)
    // k9 |t|^2hi.1  k10 |t|^2lo.1  k11 1.|q|^2hi  k12 1.|q|^2lo
    const int sbase = blockIdx.y * TPS;
    for (int rep = 0; rep < TPS / BLK; ++rep) {
        const int tgt = rep * BLK + threadIdx.x;
        const int j   = sbase + tgt;
        const float tx = t[3 * j], ty = t[3 * j + 1], tz = t[3 * j + 2];
        const float t2 = fmaf(tx, tx, fmaf(ty, ty, tz * tz));
        unsigned short hx, lx, hy, ly, hz, lz, h2, l2;
        bsplit(tx, hx, lx); bsplit(ty, hy, ly); bsplit(tz, hz, lz); bsplit(t2, h2, l2);
        union { short8 v; unsigned short s[8]; } k0, k1;
        k0.s[0]=hx; k0.s[1]=hy; k0.s[2]=hz; k0.s[3]=hx; k0.s[4]=hy; k0.s[5]=hz; k0.s[6]=lx; k0.s[7]=ly;
        k1.s[0]=lz; k1.s[1]=h2; k1.s[2]=l2; k1.s[3]=0x3F80; k1.s[4]=0x3F80; k1.s[5]=0; k1.s[6]=0; k1.s[7]=0;
        const int tile = tgt >> 5, row = tgt & 31;
        frag[tile * 64 + row]      = k0.v;                 // k-half 0 (lanes 0-31)
        frag[tile * 64 + 32 + row] = k1.v;                 // k-half 1 (lanes 32-63)
    }

    // four B-frags per wave: query cols qiA, +128, +256, +384
    const int lane = threadIdx.x & 63;
    const int wave = threadIdx.x >> 6;
    const int kh   = lane >> 5;
    const int qiA  = blockIdx.x * QPB + wave * 32 + (lane & 31);
    const int qiB  = qiA + 128;
    const int qiC  = qiA + 256;
    const int qiD  = qiA + 384;
    const short8 bfragA = make_bfrag(q[3*qiA], q[3*qiA+1], q[3*qiA+2], kh);
    const short8 bfragB = make_bfrag(q[3*qiB], q[3*qiB+1], q[3*qiB+2], kh);
    const short8 bfragC = make_bfrag(q[3*qiC], q[3*qiC+1], q[3*qiC+2], kh);
    const short8 bfragD = make_bfrag(q[3*qiD], q[3*qiD+1], q[3*qiD+2], kh);

    __syncthreads();

    const float16v zz = {0.f,0.f,0.f,0.f, 0.f,0.f,0.f,0.f,
                         0.f,0.f,0.f,0.f, 0.f,0.f,0.f,0.f};
    const size_t gqA = (size_t)bz * N + qiA;
    float gminA = 3.402823466e38f, gminB = 3.402823466e38f;
    float gminC = 3.402823466e38f, gminD = 3.402823466e38f;

    // hot loop: 1 ds_read_b128 + 4 independent MFMA + 4 min3 trees per tile
    #pragma unroll 2
    for (int tile = 0; tile < TILES; ++tile) {
        const short8 av = frag[tile * 64 + lane];
        const float16v aA = __builtin_amdgcn_mfma_f32_32x32x16_bf16(av, bfragA, zz, 0, 0, 0);
        const float16v aB = __builtin_amdgcn_mfma_f32_32x32x16_bf16(av, bfragB, zz, 0, 0, 0);
        const float16v aC = __builtin_amdgcn_mfma_f32_32x32x16_bf16(av, bfragC, zz, 0, 0, 0);
        const float16v aD = __builtin_amdgcn_mfma_f32_32x32x16_bf16(av, bfragD, zz, 0, 0, 0);
        gminA = fminf(gminA, tree16(aA));
        gminB = fminf(gminB, tree16(aB));
        gminC = fminf(gminC, tree16(aC));
        gminD = fminf(gminD, tree16(aD));
        if ((tile & 7) == 7) {                             // close a 256-target group
            const size_t rbase =
                (size_t)(blockIdx.y * (TILES / 8) + (tile >> 3)) * total;
            const float oA = fminf(gminA, __shfl_xor(gminA, 32, 64));
            const float oB = fminf(gminB, __shfl_xor(gminB, 32, 64));
            const float oC = fminf(gminC, __shfl_xor(gminC, 32, 64));
            const float oD = fminf(gminD, __shfl_xor(gminD, 32, 64));
            if (lane < 32) {
                slot[rbase + gqA]       = oA;
                slot[rbase + gqA + 128] = oB;
                slot[rbase + gqA + 256] = oC;
                slot[rbase + gqA + 384] = oD;
            }
            gminA = 3.402823466e38f; gminB = 3.402823466e38f;
            gminC = 3.402823466e38f; gminD = 3.402823466e38f;
        }
    }
}

__device__ inline float sq3(float x, float y, float z) {
    return fmaf(x, x, fmaf(y, y, z * z));
}

// 8 exact distances from 6 named float4 (12B per target) — no indexable array
#define DIST8(V0,V1,V2,V3,V4,V5,BASE)                                          \
    do {                                                                       \
        const float d0 = sq3(qx-(V0).x, qy-(V0).y, qz-(V0).z);                 \
        const float d1 = sq3(qx-(V0).w, qy-(V1).x, qz-(V1).y);                 \
        const float d2 = sq3(qx-(V1).z, qy-(V1).w, qz-(V2).x);                 \
        const float d3 = sq3(qx-(V2).y, qy-(V2).z, qz-(V2).w);                 \
        const float d4 = sq3(qx-(V3).x, qy-(V3).y, qz-(V3).z);                 \
        const float d5 = sq3(qx-(V3).w, qy-(V4).x, qz-(V4).y);                 \
        const float d6 = sq3(qx-(V4).z, qy-(V4).w, qz-(V5).x);                 \
        const float d7 = sq3(qx-(V5).y, qy-(V5).z, qz-(V5).w);                 \
        best = min(best, (__float_as_uint(d0) & 0xFFFFFF00u) | (unsigned)((BASE)+0)); \
        best = min(best, (__float_as_uint(d1) & 0xFFFFFF00u) | (unsigned)((BASE)+1)); \
        best = min(best, (__float_as_uint(d2) & 0xFFFFFF00u) | (unsigned)((BASE)+2)); \
        best = min(best, (__float_as_uint(d3) & 0xFFFFFF00u) | (unsigned)((BASE)+3)); \
        best = min(best, (__float_as_uint(d4) & 0xFFFFFF00u) | (unsigned)((BASE)+4)); \
        best = min(best, (__float_as_uint(d5) & 0xFFFFFF00u) | (unsigned)((BASE)+5)); \
        best = min(best, (__float_as_uint(d6) & 0xFFFFFF00u) | (unsigned)((BASE)+6)); \
        best = min(best, (__float_as_uint(d7) & 0xFFFFFF00u) | (unsigned)((BASE)+7)); \
    } while (0)

// A1 + A2 + count; 1024 blocks, 4 workers/query, NO barrier.
// Result reuse: d -> slot row 0, idxg -> slot row 1 (rows dead after A1).
__global__ __launch_bounds__(BLK) void dacl_merge(
    const float* __restrict__ gts, const float* __restrict__ preds,
    float* __restrict__ slot, int* __restrict__ cnt,
    float* __restrict__ out, int out_size, int B, int N)
{
    const int tid  = threadIdx.x;
    const int lane = tid & 63;       // local query 0..63
    const int wv   = tid >> 6;       // sub-worker 0..3
    const int total = 2 * B * N;
    const int g0   = blockIdx.x * FQ;                      // first query of block
    const int bz   = g0 / N;                               // block-uniform
    const int dir  = bz / B;
    const int b    = bz - dir * B;
    const float* __restrict__ q = (dir == 0 ? gts : preds) + (size_t)b * N * 3;
    const float* __restrict__ t = (dir == 0 ? preds : gts) + (size_t)b * N * 3;

    __shared__ unsigned int smin[FQ];   // A1: trunc-monotone | group5
    __shared__ unsigned int skey[FQ];   // A2: bits(d)&~0xFF | idx8

    if (blockIdx.x == 0 && tid < out_size) out[tid] = 0.0f;
    if (tid < FQ) { smin[tid] = 0xFFFFFFFFu; skey[tid] = 0xFFFFFFFFu; }
    __syncthreads();

    const int g = g0 + lane;                               // this query id

    // A1: wave wv scans group rows [wv*8, wv*8+8); coalesced per row
    {
        unsigned int pk = 0xFFFFFFFFu;
        #pragma unroll
        for (int s = wv * 8; s < wv * 8 + 8; ++s) {
            const unsigned int ub0 = __float_as_uint(slot[(size_t)s * total + g]);
            const unsigned int ub  = ((int)ub0 < 0) ? ~ub0 : (ub0 | 0x80000000u);
            pk = min(pk, (ub & 0xFFFFFFE0u) | (unsigned int)s);
        }
        atomicMin(&smin[lane], pk);                        // LDS; ties -> low group
    }
    __syncthreads();
    const int gr = (int)(smin[lane] & 31u);

    // A2: 4 workers/query, 64 exact targets each, 8 per step via named float4
    const float qx = q[3 * (g - bz * N)], qy = q[3 * (g - bz * N) + 1],
                qz = q[3 * (g - bz * N) + 2];
    {
        const float4* __restrict__ tb4 =
            (const float4*)(t + (size_t)gr * GRP * 3) + wv * 48;
        unsigned int best = 0xFFFFFFFFu;
        #pragma unroll
        for (int c = 0; c < 8; ++c) {                      // 8 x 8 targets
            const float4 v0 = tb4[c * 6 + 0];
            const float4 v1 = tb4[c * 6 + 1];
            const float4 v2 = tb4[c * 6 + 2];
            const float4 v3 = tb4[c * 6 + 3];
            const float4 v4 = tb4[c * 6 + 4];
            const float4 v5 = tb4[c * 6 + 5];
            DIST8(v0, v1, v2, v3, v4, v5, wv * 64 + c * 8);
        }
        atomicMin(&skey[lane], best);                      // LDS; first-min idx8
    }
    __syncthreads();

    if (tid < FQ) {
        const unsigned int key = skey[tid];
        const int idxg = (int)(smin[tid] & 31u) * GRP + (int)(key & 255u);
        slot[g0 + tid]                 = __uint_as_float(key & 0xFFFFFF00u); // d
        ((int*)slot)[total + g0 + tid] = idxg;                               // idx
        atomicAdd(&cnt[bz * N + idxg], 1);
    }
}

__global__ __launch_bounds__(256) void dacl_loss(
    const float* __restrict__ slot, const int* __restrict__ cnt,
    float* __restrict__ out, int B, int N)
{
    const int g  = blockIdx.x * 256 + threadIdx.x;         // query id
    const int total = 2 * B * N;
    const int bz = g / N;
    const int b  = bz - (bz / B) * B;

    const float d   = slot[g];                             // exact (<=2^-15 trunc)
    const int   idx = ((const int*)slot)[total + g];
    const float c   = (float)cnt[bz * N + idx];            // count^1 (lambda=1)
    float sv = 1.0f - expf(-d) / (c + 1e-6f);              // frac terms = 1
    #pragma unroll
    for (int off = 32; off > 0; off >>= 1) sv += __shfl_down(sv, off, 64);
    if ((threadIdx.x & 63) == 0)
        atomicAdd(&out[b], sv / (2.0f * (float)N));        // (mean1+mean2)/2
}

extern "C" void kernel_launch(void* const* d_in, const int* in_sizes, int n_in,
                              void* d_out, int out_size, void* d_ws, size_t ws_size,
                              hipStream_t stream)
{
    const float* gts   = (const float*)d_in[0];
    const float* preds = (const float*)d_in[1];

    const int N = NPTS;
    const int B = in_sizes[0] / (N * 3);                   // = 4

    const size_t nTot = (size_t)2 * B * N;                 // 65536 queries
    float* slot = (float*)d_ws;                            // NGRP x nTot (8.4MB)
    int*   cnt  = (int*)((char*)d_ws + (size_t)NGRP * nTot * sizeof(float));

    dim3 gA(QCH, NSLICE, 2 * B);                           // 16 x 8 x 8 = 1024 blocks
    dacl_partial<<<gA, BLK, 0, stream>>>(gts, preds, slot, cnt, B, N);

    dacl_merge<<<(int)(nTot / FQ), BLK, 0, stream>>>(      // 1024 blocks
        gts, preds, slot, cnt, (float*)d_out, out_size, B, N);

    dacl_loss<<<(int)(nTot / 256), 256, 0, stream>>>(      // 256 blocks
        slot, cnt, (float*)d_out, B, N);
}